// Round 1
// baseline (5300.831 us; speedup 1.0000x reference)
//
#include <hip/hip_runtime.h>

#define N_NODES 50000

typedef __bf16 bf16x8 __attribute__((ext_vector_type(8)));
typedef float f32x4 __attribute__((ext_vector_type(4)));

__device__ __forceinline__ unsigned short f2bf(float f){
  unsigned int u = __float_as_uint(f);
  u = (u + 0x7fffu + ((u >> 16) & 1u)) >> 16;
  return (unsigned short)u;
}
__device__ __forceinline__ float sigm(float x){ return 1.0f / (1.0f + __expf(-x)); }
__device__ __forceinline__ float tanh_(float x){ return 1.0f - 2.0f / (__expf(2.0f*x) + 1.0f); }

// ---------------- CSR build ----------------
__global__ void k_count(const int* __restrict__ dst, int* __restrict__ degi, int E){
  int e = blockIdx.x*256 + threadIdx.x;
  if (e < E) atomicAdd(&degi[dst[e]], 1);
}

__global__ __launch_bounds__(1024) void k_scanoff(const int* __restrict__ degi,
                                                  int* __restrict__ off, int* __restrict__ cur){
  __shared__ int part[1024];
  const int t = threadIdx.x;
  const int chunk = 49;                      // 1024*49 = 50176 >= 50000
  const int base = t * chunk;
  int s = 0;
  for (int i=0;i<chunk;++i){ int idx = base+i; if (idx < N_NODES) s += degi[idx]; }
  part[t] = s;
  __syncthreads();
  for (int d=1; d<1024; d<<=1){
    int v = part[t];
    int add = (t >= d) ? part[t-d] : 0;
    __syncthreads();
    part[t] = v + add;
    __syncthreads();
  }
  int run = (t == 0) ? 0 : part[t-1];
  for (int i=0;i<chunk;++i){
    int idx = base+i;
    if (idx < N_NODES){ off[idx] = run; cur[idx] = run; run += degi[idx]; }
  }
  if (t == 1023) off[N_NODES] = part[1023];
}

__global__ void k_fill(const int* __restrict__ src, const int* __restrict__ dst,
                       int* __restrict__ cur, int* __restrict__ eidx, int E){
  int e = blockIdx.x*256 + threadIdx.x;
  if (e < E){
    int p = atomicAdd(&cur[dst[e]], 1);
    eidx[p] = src[e];
  }
}

// ---------------- mean aggregation (gather, float4 lanes) ----------------
__global__ __launch_bounds__(256) void k_gmean128(const float* __restrict__ xin,
    const int* __restrict__ off, const int* __restrict__ eidx, float* __restrict__ mr){
  const int node = blockIdx.x*8 + (threadIdx.x >> 5);   // 32 lanes per node
  const int k4 = threadIdx.x & 31;                      // float4 index, 32*4=128
  const int e0 = off[node], e1 = off[node+1];
  float4 s = make_float4(0.f,0.f,0.f,0.f);
  for (int e = e0; e < e1; ++e){
    const float4 v = *(const float4*)(xin + (size_t)eidx[e]*128 + k4*4);
    s.x += v.x; s.y += v.y; s.z += v.z; s.w += v.w;
  }
  const float d = fmaxf((float)(e1-e0), 1.0f);
  s.x /= d; s.y /= d; s.z /= d; s.w /= d;
  *(float4*)(mr + (size_t)node*128 + k4*4) = s;
}

__global__ __launch_bounds__(256) void k_gmean256(const float* __restrict__ xin,
    const int* __restrict__ off, const int* __restrict__ eidx, float* __restrict__ mr){
  const int node = blockIdx.x*4 + (threadIdx.x >> 6);   // 64 lanes per node
  const int k4 = threadIdx.x & 63;                      // 64*4 = 256
  const int e0 = off[node], e1 = off[node+1];
  float4 s = make_float4(0.f,0.f,0.f,0.f);
  for (int e = e0; e < e1; ++e){
    const float4 v = *(const float4*)(xin + (size_t)eidx[e]*256 + k4*4);
    s.x += v.x; s.y += v.y; s.z += v.z; s.w += v.w;
  }
  const float d = fmaxf((float)(e1-e0), 1.0f);
  s.x /= d; s.y /= d; s.z /= d; s.w /= d;
  *(float4*)(mr + (size_t)node*256 + k4*4) = s;
}

// ---------------- fused SAGE + skip-MLP layer 1 (16 nodes/block, 4h x 4n tiles) ----------------
__global__ __launch_bounds__(256) void k_layer1(
  const float* __restrict__ x, const float* __restrict__ mrg,
  const float* __restrict__ wl, const float* __restrict__ bl, const float* __restrict__ wr,
  const float* __restrict__ s1w, const float* __restrict__ s1b,
  const float* __restrict__ s2w, const float* __restrict__ s2b,
  float* __restrict__ u1, float* __restrict__ m1)
{
  const int n0 = blockIdx.x * 16;
  const int tid = threadIdx.x;
  __shared__ __align__(16) float xr[16][128];
  __shared__ __align__(16) float mr[16][128];
  __shared__ __align__(16) float t1[16][128];
  {
    const float4* xs = (const float4*)(x + (size_t)n0*128);
    const float4* ms = (const float4*)(mrg + (size_t)n0*128);
    float4* xd = (float4*)&xr[0][0];
    float4* md = (float4*)&mr[0][0];
    xd[tid] = xs[tid]; xd[tid+256] = xs[tid+256];
    md[tid] = ms[tid]; md[tid+256] = ms[tid+256];
  }
  __syncthreads();
  // skip MLP hidden: t1[i][j] = relu(s1w[j,:]·x[i,:] + s1b[j])
  {
    const int j = tid & 127, half = tid >> 7;
    float acc[8] = {0,0,0,0,0,0,0,0};
    const float4* w4 = (const float4*)(s1w + (size_t)j*128);
    for (int k4=0;k4<32;++k4){
      const float4 wv = w4[k4];
      #pragma unroll
      for (int i=0;i<8;++i){
        const float4 xv = *(const float4*)&xr[half*8+i][k4*4];
        acc[i] += wv.x*xv.x + wv.y*xv.y + wv.z*xv.z + wv.w*xv.w;
      }
    }
    const float b = s1b[j];
    #pragma unroll
    for (int i=0;i<8;++i) t1[half*8+i][j] = fmaxf(acc[i] + b, 0.f);
  }
  __syncthreads();
  // conv (wl·mr + wr·xr) and skip out (s2w·t1), 4 h-channels x 4 nodes per thread
  {
    const int hh = tid & 63;      // h = 4*hh .. 4*hh+3
    const int grp = tid >> 6;     // nodes 4*grp .. 4*grp+3
    const int i0 = grp*4;
    const int h0 = hh*4;
    float au[4][4], am[4][4];
    #pragma unroll
    for (int a=0;a<4;++a)
      #pragma unroll
      for (int b=0;b<4;++b){ au[a][b]=0.f; am[a][b]=0.f; }
    for (int k4=0;k4<32;++k4){
      float4 wlv[4], wrv[4], w2v[4];
      #pragma unroll
      for (int a=0;a<4;++a){
        wlv[a] = *(const float4*)(wl  + (size_t)(h0+a)*128 + k4*4);
        wrv[a] = *(const float4*)(wr  + (size_t)(h0+a)*128 + k4*4);
        w2v[a] = *(const float4*)(s2w + (size_t)(h0+a)*128 + k4*4);
      }
      #pragma unroll
      for (int b=0;b<4;++b){
        const float4 m  = *(const float4*)&mr[i0+b][k4*4];
        const float4 xv = *(const float4*)&xr[i0+b][k4*4];
        const float4 t  = *(const float4*)&t1[i0+b][k4*4];
        #pragma unroll
        for (int a=0;a<4;++a){
          au[a][b] += wlv[a].x*m.x + wlv[a].y*m.y + wlv[a].z*m.z + wlv[a].w*m.w
                    + wrv[a].x*xv.x + wrv[a].y*xv.y + wrv[a].z*xv.z + wrv[a].w*xv.w;
          am[a][b] += w2v[a].x*t.x + w2v[a].y*t.y + w2v[a].z*t.z + w2v[a].w*t.w;
        }
      }
    }
    const float bl0=bl[h0], bl1=bl[h0+1], bl2=bl[h0+2], bl3=bl[h0+3];
    const float b20=s2b[h0], b21=s2b[h0+1], b22=s2b[h0+2], b23=s2b[h0+3];
    #pragma unroll
    for (int b=0;b<4;++b){
      float4 uo, mo;
      uo.x = au[0][b]+bl0; uo.y = au[1][b]+bl1; uo.z = au[2][b]+bl2; uo.w = au[3][b]+bl3;
      mo.x = am[0][b]+b20; mo.y = am[1][b]+b21; mo.z = am[2][b]+b22; mo.w = am[3][b]+b23;
      *(float4*)(u1 + (size_t)(n0+i0+b)*256 + h0) = uo;
      *(float4*)(m1 + (size_t)(n0+i0+b)*256 + h0) = mo;
    }
  }
}

// ---------------- fused SAGE + skip-MLP layer 2 (K=256 conv, K=128 skip) ----------------
__global__ __launch_bounds__(256) void k_layer2(
  const float* __restrict__ x1, const float* __restrict__ mrg,
  const float* __restrict__ wl, const float* __restrict__ bl, const float* __restrict__ wr,
  const float* __restrict__ s1w, const float* __restrict__ s1b,
  const float* __restrict__ s2w, const float* __restrict__ s2b,
  float* __restrict__ u2, float* __restrict__ m2)
{
  const int n0 = blockIdx.x * 16;
  const int tid = threadIdx.x;
  __shared__ __align__(16) float xr[16][256];
  __shared__ __align__(16) float mr[16][256];
  __shared__ __align__(16) float t2[16][128];
  {
    const float4* xs = (const float4*)(x1 + (size_t)n0*256);
    const float4* ms = (const float4*)(mrg + (size_t)n0*256);
    float4* xd = (float4*)&xr[0][0];
    float4* md = (float4*)&mr[0][0];
    #pragma unroll
    for (int q=0;q<4;++q){ xd[tid+q*256] = xs[tid+q*256]; md[tid+q*256] = ms[tid+q*256]; }
  }
  __syncthreads();
  // skip MLP hidden: t2[i][j] = relu(s1w[j,:]·x1[i,:] + s1b[j]), K=256
  {
    const int j = tid & 127, half = tid >> 7;
    float acc[8] = {0,0,0,0,0,0,0,0};
    const float4* w4 = (const float4*)(s1w + (size_t)j*256);
    for (int k4=0;k4<64;++k4){
      const float4 wv = w4[k4];
      #pragma unroll
      for (int i=0;i<8;++i){
        const float4 xv = *(const float4*)&xr[half*8+i][k4*4];
        acc[i] += wv.x*xv.x + wv.y*xv.y + wv.z*xv.z + wv.w*xv.w;
      }
    }
    const float b = s1b[j];
    #pragma unroll
    for (int i=0;i<8;++i) t2[half*8+i][j] = fmaxf(acc[i] + b, 0.f);
  }
  __syncthreads();
  {
    const int hh = tid & 63;
    const int grp = tid >> 6;
    const int i0 = grp*4;
    const int h0 = hh*4;
    float au[4][4], am[4][4];
    #pragma unroll
    for (int a=0;a<4;++a)
      #pragma unroll
      for (int b=0;b<4;++b){ au[a][b]=0.f; am[a][b]=0.f; }
    // conv part, K=256
    for (int k4=0;k4<64;++k4){
      float4 wlv[4], wrv[4];
      #pragma unroll
      for (int a=0;a<4;++a){
        wlv[a] = *(const float4*)(wl + (size_t)(h0+a)*256 + k4*4);
        wrv[a] = *(const float4*)(wr + (size_t)(h0+a)*256 + k4*4);
      }
      #pragma unroll
      for (int b=0;b<4;++b){
        const float4 m  = *(const float4*)&mr[i0+b][k4*4];
        const float4 xv = *(const float4*)&xr[i0+b][k4*4];
        #pragma unroll
        for (int a=0;a<4;++a){
          au[a][b] += wlv[a].x*m.x + wlv[a].y*m.y + wlv[a].z*m.z + wlv[a].w*m.w
                    + wrv[a].x*xv.x + wrv[a].y*xv.y + wrv[a].z*xv.z + wrv[a].w*xv.w;
        }
      }
    }
    // skip out part, K=128
    for (int k4=0;k4<32;++k4){
      float4 w2v[4];
      #pragma unroll
      for (int a=0;a<4;++a) w2v[a] = *(const float4*)(s2w + (size_t)(h0+a)*128 + k4*4);
      #pragma unroll
      for (int b=0;b<4;++b){
        const float4 t = *(const float4*)&t2[i0+b][k4*4];
        #pragma unroll
        for (int a=0;a<4;++a)
          am[a][b] += w2v[a].x*t.x + w2v[a].y*t.y + w2v[a].z*t.z + w2v[a].w*t.w;
      }
    }
    const float bl0=bl[h0], bl1=bl[h0+1], bl2=bl[h0+2], bl3=bl[h0+3];
    const float b20=s2b[h0], b21=s2b[h0+1], b22=s2b[h0+2], b23=s2b[h0+3];
    #pragma unroll
    for (int b=0;b<4;++b){
      float4 uo, mo;
      uo.x = au[0][b]+bl0; uo.y = au[1][b]+bl1; uo.z = au[2][b]+bl2; uo.w = au[3][b]+bl3;
      mo.x = am[0][b]+b20; mo.y = am[1][b]+b21; mo.z = am[2][b]+b22; mo.w = am[3][b]+b23;
      *(float4*)(u2 + (size_t)(n0+i0+b)*256 + h0) = uo;
      *(float4*)(m2 + (size_t)(n0+i0+b)*256 + h0) = mo;
    }
  }
}

// ---------------- BatchNorm ----------------
__global__ __launch_bounds__(256) void k_bnstats(const float* __restrict__ u, float* __restrict__ st, int N){
  int h = threadIdx.x;
  float s=0.f, s2=0.f;
  for (int n = blockIdx.x; n < N; n += gridDim.x){
    float v = u[(size_t)n*256 + h];
    s += v; s2 += v*v;
  }
  atomicAdd(&st[h], s);
  atomicAdd(&st[256+h], s2);
}

__global__ void k_bnparams(const float* __restrict__ st, const float* __restrict__ g,
                           const float* __restrict__ b, float* __restrict__ ab, float invN){
  int h = threadIdx.x;
  float mean = st[h]*invN;
  float var = st[256+h]*invN - mean*mean;
  float a = g[h] * rsqrtf(var + 1e-5f);
  ab[h] = a;
  ab[256+h] = b[h] - mean*a;
}

__global__ __launch_bounds__(256) void k_combine(const float* __restrict__ u, const float* __restrict__ m,
    const float* __restrict__ ab, float* __restrict__ xo, unsigned short* __restrict__ xb){
  int i = blockIdx.x*256 + threadIdx.x;     // grid covers exactly N*256
  int h = i & 255;
  float v = u[i]*ab[h] + ab[256+h] + m[i];
  v = fmaxf(v, 0.f);
  if (xo) xo[i] = v;
  if (xb) xb[i] = f2bf(v);
}

// ---------------- LSTM input projection ----------------
__global__ __launch_bounds__(512) void k_gx(const float* __restrict__ trace,
  const float* __restrict__ wihf, const float* __restrict__ bihf, const float* __restrict__ bhhf,
  const float* __restrict__ wihb, const float* __restrict__ bihb, const float* __restrict__ bhhb,
  float* __restrict__ gx)
{
  const int blk = blockIdx.x;       // dir*512 + tt
  const int tt = blk & 511;
  const int dir = blk >> 9;
  const float* wih = dir ? wihb : wihf;
  const float* bi  = dir ? bihb : bihf;
  const float* bh  = dir ? bhhb : bhhf;
  __shared__ float tr[4][128];
  const int j = threadIdx.x;
  { int b = j >> 7, k = j & 127; tr[b][k] = trace[((size_t)b*512 + tt)*128 + k]; }
  __syncthreads();
  const float* w = wih + (size_t)j*128;
  float a0=0.f,a1=0.f,a2=0.f,a3=0.f;
  for (int k=0;k<128;++k){
    float wv = w[k];
    a0 += wv*tr[0][k]; a1 += wv*tr[1][k]; a2 += wv*tr[2][k]; a3 += wv*tr[3][k];
  }
  float bias = bi[j] + bh[j];
  size_t base = (size_t)blk*2048 + j;
  gx[base        ] = a0 + bias;
  gx[base +  512 ] = a1 + bias;
  gx[base + 1024 ] = a2 + bias;
  gx[base + 1536 ] = a3 + bias;
}

// ---------------- persistent LSTM scan: 8 blocks = (dir, batch) ----------------
__global__ __launch_bounds__(512) void k_scan(const float* __restrict__ gx,
    const float* __restrict__ whh_f, const float* __restrict__ whh_b,
    unsigned short* __restrict__ Yb)
{
  const int dir = blockIdx.x >> 2;
  const int b   = blockIdx.x & 3;
  const int j   = threadIdx.x;
  const float* whh = dir ? whh_b : whh_f;
  float w[128];
  {
    const float4* wp = (const float4*)(whh + (size_t)j*128);
    #pragma unroll
    for (int q=0;q<32;++q){ float4 v = wp[q]; w[4*q]=v.x; w[4*q+1]=v.y; w[4*q+2]=v.z; w[4*q+3]=v.w; }
  }
  __shared__ __align__(16) float hbuf[128];
  __shared__ float gbuf[512];
  if (j < 128) hbuf[j] = 0.f;
  float c = 0.f;
  __syncthreads();
  for (int t=0;t<512;++t){
    const int tt = dir ? (511-t) : t;
    float acc = gx[(((size_t)dir*512 + tt)*4 + b)*512 + j];
    const float4* hp = (const float4*)hbuf;
    #pragma unroll
    for (int q=0;q<32;++q){
      float4 hv = hp[q];
      acc += w[4*q]*hv.x + w[4*q+1]*hv.y + w[4*q+2]*hv.z + w[4*q+3]*hv.w;
    }
    gbuf[j] = acc;
    __syncthreads();
    if (j < 128){
      float ig = sigm(gbuf[j]);
      float fg = sigm(gbuf[j+128]);
      float gg = tanh_(gbuf[j+256]);
      float og = sigm(gbuf[j+384]);
      c = fg*c + ig*gg;
      float h = og * tanh_(c);
      hbuf[j] = h;
      Yb[((size_t)(b*512 + tt))*256 + dir*128 + j] = f2bf(h);
    }
    __syncthreads();
  }
}

// ---------------- final einsum: [2048,256] x [50000,256]^T via bf16 MFMA ----------------
__global__ __launch_bounds__(256) void k_einsum(const unsigned short* __restrict__ Yb,
    const unsigned short* __restrict__ Xb, float* __restrict__ out)
{
  const int wave = threadIdx.x >> 6;
  const int lane = threadIdx.x & 63;
  const int ntile = blockIdx.y*4 + wave;
  if (ntile >= 3125) return;
  const int m0 = blockIdx.x << 4;
  const int n0 = ntile << 4;
  const int la = lane & 15, q = lane >> 4;
  const bf16x8* pa = (const bf16x8*)(Yb + (size_t)(m0 + la)*256 + q*8);
  const bf16x8* pb = (const bf16x8*)(Xb + (size_t)(n0 + la)*256 + q*8);
  f32x4 acc = {0.f,0.f,0.f,0.f};
  #pragma unroll
  for (int kk=0; kk<8; ++kk){
    acc = __builtin_amdgcn_mfma_f32_16x16x32_bf16(pa[kk*4], pb[kk*4], acc, 0, 0, 0);
  }
  const int col = n0 + la;
  const size_t base = (size_t)(m0 + q*4)*50000 + col;
  out[base         ] = acc[0];
  out[base +  50000] = acc[1];
  out[base + 100000] = acc[2];
  out[base + 150000] = acc[3];
}

extern "C" void kernel_launch(void* const* d_in, const int* in_sizes, int n_in,
                              void* d_out, int out_size, void* d_ws, size_t ws_size,
                              hipStream_t stream) {
  const float* trace = (const float*)d_in[0];
  const float* x     = (const float*)d_in[1];
  const int*   ei    = (const int*)d_in[2];
  const float* c1wl = (const float*)d_in[3];
  const float* c1bl = (const float*)d_in[4];
  const float* c1wr = (const float*)d_in[5];
  const float* c2wl = (const float*)d_in[6];
  const float* c2bl = (const float*)d_in[7];
  const float* c2wr = (const float*)d_in[8];
  const float* s1w1 = (const float*)d_in[9];
  const float* s1b1 = (const float*)d_in[10];
  const float* s1w2 = (const float*)d_in[11];
  const float* s1b2 = (const float*)d_in[12];
  const float* s2w1 = (const float*)d_in[13];
  const float* s2b1 = (const float*)d_in[14];
  const float* s2w2 = (const float*)d_in[15];
  const float* s2b2 = (const float*)d_in[16];
  const float* bn1g = (const float*)d_in[17];
  const float* bn1b = (const float*)d_in[18];
  const float* bn2g = (const float*)d_in[19];
  const float* bn2b = (const float*)d_in[20];
  const float* wihf = (const float*)d_in[21];
  const float* whhf = (const float*)d_in[22];
  const float* bihf = (const float*)d_in[23];
  const float* bhhf = (const float*)d_in[24];
  const float* wihb = (const float*)d_in[25];
  const float* whhb = (const float*)d_in[26];
  const float* bihb = (const float*)d_in[27];
  const float* bhhb = (const float*)d_in[28];
  const int E = in_sizes[2] / 2;
  const int* srcv = ei;
  const int* dstv = ei + E;

  char* W = (char*)d_ws;
  int*   degi  = (int*)(W + 0);           // 50000 ints
  int*   offp  = (int*)(W + 200704);      // 50001 ints
  int*   cur   = (int*)(W + 401408);      // 50000 ints
  int*   eidx  = (int*)(W + 602112);      // 800000 ints
  float* stats = (float*)(W + 3802112);   // 2048 f: stats1, ab1, stats2, ab2
  float* mr1   = (float*)(W + 3810304);   // 50000x128
  float* SA    = (float*)(W + 29410304);  // u1, then mr2
  float* SB    = (float*)(W + 80610304);  // m1, then u2
  float* SC    = (float*)(W + 131810304); // x1, then m2
  float* gx    = (float*)(W + 183010304); // 2x512x4x512
  unsigned short* x2bf = (unsigned short*)(W + 191398912); // 50000x256 bf16
  unsigned short* Ybf  = (unsigned short*)(W + 216998912); // 2048x256 bf16
  float* out = (float*)d_out;

  hipMemsetAsync(degi, 0, 200704, stream);
  hipMemsetAsync(stats, 0, 2048*sizeof(float), stream);

  k_count   <<<(E+255)/256, 256, 0, stream>>>(dstv, degi, E);
  k_scanoff <<<1, 1024, 0, stream>>>(degi, offp, cur);
  k_fill    <<<(E+255)/256, 256, 0, stream>>>(srcv, dstv, cur, eidx, E);

  k_gmean128<<<N_NODES/8, 256, 0, stream>>>(x, offp, eidx, mr1);
  k_layer1  <<<N_NODES/16, 256, 0, stream>>>(x, mr1, c1wl, c1bl, c1wr, s1w1, s1b1, s1w2, s1b2, SA, SB);
  k_bnstats <<<256, 256, 0, stream>>>(SA, stats, N_NODES);
  k_bnparams<<<1, 256, 0, stream>>>(stats, bn1g, bn1b, stats+512, 1.0f/N_NODES);
  k_combine <<<N_NODES, 256, 0, stream>>>(SA, SB, stats+512, SC, (unsigned short*)nullptr);

  k_gmean256<<<N_NODES/4, 256, 0, stream>>>(SC, offp, eidx, SA);
  k_layer2  <<<N_NODES/16, 256, 0, stream>>>(SC, SA, c2wl, c2bl, c2wr, s2w1, s2b1, s2w2, s2b2, SB, SC);
  k_bnstats <<<256, 256, 0, stream>>>(SB, stats+1024, N_NODES);
  k_bnparams<<<1, 256, 0, stream>>>(stats+1024, bn2g, bn2b, stats+1536, 1.0f/N_NODES);
  k_combine <<<N_NODES, 256, 0, stream>>>(SB, SC, stats+1536, (float*)nullptr, x2bf);

  k_gx      <<<1024, 512, 0, stream>>>(trace, wihf, bihf, bhhf, wihb, bihb, bhhb, gx);
  k_scan    <<<8, 512, 0, stream>>>(gx, whhf, whhb, Ybf);

  k_einsum  <<<dim3(128, 782), 256, 0, stream>>>(Ybf, x2bf, out);

  (void)n_in; (void)out_size; (void)ws_size;
}

// Round 2
// 2713.606 us; speedup vs baseline: 1.9534x; 1.9534x over previous
//
#include <hip/hip_runtime.h>

#define N_NODES 50000
#define GF_ACC  1
#define GF_RELU 2

typedef __bf16 bf16x8 __attribute__((ext_vector_type(8)));
typedef float f32x4 __attribute__((ext_vector_type(4)));

__device__ __forceinline__ unsigned short f2bf(float f){
  unsigned int u = __float_as_uint(f);
  u = (u + 0x7fffu + ((u >> 16) & 1u)) >> 16;
  return (unsigned short)u;
}
__device__ __forceinline__ float sigm(float x){ return 1.0f / (1.0f + __expf(-x)); }
__device__ __forceinline__ float tanh_(float x){ return 1.0f - 2.0f / (__expf(2.0f*x) + 1.0f); }

// ---------------- CSR build ----------------
__global__ void k_count(const int* __restrict__ dst, int* __restrict__ degi, int E){
  int e = blockIdx.x*256 + threadIdx.x;
  if (e < E) atomicAdd(&degi[dst[e]], 1);
}

__global__ __launch_bounds__(1024) void k_scanoff(const int* __restrict__ degi,
                                                  int* __restrict__ off, int* __restrict__ cur){
  __shared__ int part[1024];
  const int t = threadIdx.x;
  const int chunk = 49;                      // 1024*49 = 50176 >= 50000
  const int base = t * chunk;
  int s = 0;
  for (int i=0;i<chunk;++i){ int idx = base+i; if (idx < N_NODES) s += degi[idx]; }
  part[t] = s;
  __syncthreads();
  for (int d=1; d<1024; d<<=1){
    int v = part[t];
    int add = (t >= d) ? part[t-d] : 0;
    __syncthreads();
    part[t] = v + add;
    __syncthreads();
  }
  int run = (t == 0) ? 0 : part[t-1];
  for (int i=0;i<chunk;++i){
    int idx = base+i;
    if (idx < N_NODES){ off[idx] = run; cur[idx] = run; run += degi[idx]; }
  }
  if (t == 1023) off[N_NODES] = part[1023];
}

__global__ void k_fill(const int* __restrict__ src, const int* __restrict__ dst,
                       int* __restrict__ cur, int* __restrict__ eidx, int E){
  int e = blockIdx.x*256 + threadIdx.x;
  if (e < E){
    int p = atomicAdd(&cur[dst[e]], 1);
    eidx[p] = src[e];
  }
}

// ---------------- mean aggregation (gather, float4 lanes) ----------------
__global__ __launch_bounds__(256) void k_gmean128(const float* __restrict__ xin,
    const int* __restrict__ off, const int* __restrict__ eidx, float* __restrict__ mr){
  const int node = blockIdx.x*8 + (threadIdx.x >> 5);   // 32 lanes per node
  const int k4 = threadIdx.x & 31;                      // float4 index, 32*4=128
  const int e0 = off[node], e1 = off[node+1];
  float4 s = make_float4(0.f,0.f,0.f,0.f);
  for (int e = e0; e < e1; ++e){
    const float4 v = *(const float4*)(xin + (size_t)eidx[e]*128 + k4*4);
    s.x += v.x; s.y += v.y; s.z += v.z; s.w += v.w;
  }
  const float d = fmaxf((float)(e1-e0), 1.0f);
  s.x /= d; s.y /= d; s.z /= d; s.w /= d;
  *(float4*)(mr + (size_t)node*128 + k4*4) = s;
}

__global__ __launch_bounds__(256) void k_gmean256(const float* __restrict__ xin,
    const int* __restrict__ off, const int* __restrict__ eidx, float* __restrict__ mr){
  const int node = blockIdx.x*4 + (threadIdx.x >> 6);   // 64 lanes per node
  const int k4 = threadIdx.x & 63;                      // 64*4 = 256
  const int e0 = off[node], e1 = off[node+1];
  float4 s = make_float4(0.f,0.f,0.f,0.f);
  for (int e = e0; e < e1; ++e){
    const float4 v = *(const float4*)(xin + (size_t)eidx[e]*256 + k4*4);
    s.x += v.x; s.y += v.y; s.z += v.z; s.w += v.w;
  }
  const float d = fmaxf((float)(e1-e0), 1.0f);
  s.x /= d; s.y /= d; s.z /= d; s.w /= d;
  *(float4*)(mr + (size_t)node*256 + k4*4) = s;
}

// ---------------- generic fp32 tiled GEMM: C[M,N] (+)= A[M,K] @ W[N,K]^T (+bias)(relu) ----
// block tile 128x128, 256 threads, 8x8 per thread (split 4+4), BK=32
__global__ __launch_bounds__(256) void k_gemm(
  const float* __restrict__ A, const float* __restrict__ W,
  const float* __restrict__ b1, const float* __restrict__ b2,
  float* __restrict__ C, int M, int N, int K, int flags)
{
  __shared__ __align__(16) float As[32][132];
  __shared__ __align__(16) float Ws[32][132];
  const int tid = threadIdx.x;
  const int m0 = blockIdx.x * 128;
  const int n0 = blockIdx.y * 128;
  const int tx = tid & 15, ty = tid >> 4;
  const int sr = tid >> 1;             // 0..127 tile row (for staging)
  const int sc = (tid & 1) * 4;        // f4 col base: 0 or 4

  float acc[8][8];
  #pragma unroll
  for (int i=0;i<8;++i)
    #pragma unroll
    for (int j=0;j<8;++j) acc[i][j] = 0.f;

  int am = m0 + sr; if (am >= M) am = M - 1;   // clamp (stores are guarded)
  const float4* Arow = (const float4*)(A + (size_t)am*K);
  const float4* Wrow = (const float4*)(W + (size_t)(n0 + sr)*K);

  for (int k0 = 0; k0 < K; k0 += 32){
    const int f0 = k0 >> 2;
    float4 av[4], wv[4];
    #pragma unroll
    for (int q=0;q<4;++q){ av[q] = Arow[f0 + sc + q]; wv[q] = Wrow[f0 + sc + q]; }
    __syncthreads();   // previous chunk's reads done before overwrite
    #pragma unroll
    for (int q=0;q<4;++q){
      const int kk = (sc + q) * 4;
      As[kk  ][sr] = av[q].x; As[kk+1][sr] = av[q].y; As[kk+2][sr] = av[q].z; As[kk+3][sr] = av[q].w;
      Ws[kk  ][sr] = wv[q].x; Ws[kk+1][sr] = wv[q].y; Ws[kk+2][sr] = wv[q].z; Ws[kk+3][sr] = wv[q].w;
    }
    __syncthreads();
    #pragma unroll 8
    for (int k=0;k<32;++k){
      const float4 a0 = *(const float4*)&As[k][tx*4];
      const float4 a1 = *(const float4*)&As[k][tx*4 + 64];
      const float4 w0 = *(const float4*)&Ws[k][ty*4];
      const float4 w1 = *(const float4*)&Ws[k][ty*4 + 64];
      const float a[8] = {a0.x,a0.y,a0.z,a0.w, a1.x,a1.y,a1.z,a1.w};
      const float b[8] = {w0.x,w0.y,w0.z,w0.w, w1.x,w1.y,w1.z,w1.w};
      #pragma unroll
      for (int i=0;i<8;++i)
        #pragma unroll
        for (int j=0;j<8;++j) acc[i][j] += a[i]*b[j];
    }
  }

  // epilogue: bias (+bias2), optional accumulate into C, optional relu
  float bb[8];
  #pragma unroll
  for (int j=0;j<8;++j){
    const int col = n0 + ty*4 + ((j>>2)<<6) + (j&3);
    float v = b1 ? b1[col] : 0.f;
    if (b2) v += b2[col];
    bb[j] = v;
  }
  #pragma unroll
  for (int i=0;i<8;++i){
    const int m = m0 + tx*4 + ((i>>2)<<6) + (i&3);
    if (m < M){
      #pragma unroll
      for (int c=0;c<2;++c){
        const int nb = n0 + ty*4 + (c<<6);
        float4 v;
        v.x = acc[i][c*4+0] + bb[c*4+0];
        v.y = acc[i][c*4+1] + bb[c*4+1];
        v.z = acc[i][c*4+2] + bb[c*4+2];
        v.w = acc[i][c*4+3] + bb[c*4+3];
        float* cp = C + (size_t)m*N + nb;
        if (flags & GF_ACC){
          const float4 o = *(const float4*)cp;
          v.x += o.x; v.y += o.y; v.z += o.z; v.w += o.w;
        }
        if (flags & GF_RELU){
          v.x = fmaxf(v.x, 0.f); v.y = fmaxf(v.y, 0.f);
          v.z = fmaxf(v.z, 0.f); v.w = fmaxf(v.w, 0.f);
        }
        *(float4*)cp = v;
      }
    }
  }
}

// ---------------- BatchNorm ----------------
__global__ __launch_bounds__(256) void k_bnstats(const float* __restrict__ u, float* __restrict__ st, int N){
  int h = threadIdx.x;
  float s=0.f, s2=0.f;
  for (int n = blockIdx.x; n < N; n += gridDim.x){
    float v = u[(size_t)n*256 + h];
    s += v; s2 += v*v;
  }
  atomicAdd(&st[h], s);
  atomicAdd(&st[256+h], s2);
}

__global__ void k_bnparams(const float* __restrict__ st, const float* __restrict__ g,
                           const float* __restrict__ b, float* __restrict__ ab, float invN){
  int h = threadIdx.x;
  float mean = st[h]*invN;
  float var = st[256+h]*invN - mean*mean;
  float a = g[h] * rsqrtf(var + 1e-5f);
  ab[h] = a;
  ab[256+h] = b[h] - mean*a;
}

__global__ __launch_bounds__(256) void k_combine(const float* __restrict__ u, const float* __restrict__ m,
    const float* __restrict__ ab, float* __restrict__ xo, unsigned short* __restrict__ xb){
  int i = blockIdx.x*256 + threadIdx.x;     // grid covers exactly N*256
  int h = i & 255;
  float v = u[i]*ab[h] + ab[256+h] + m[i];
  v = fmaxf(v, 0.f);
  if (xo) xo[i] = v;
  if (xb) xb[i] = f2bf(v);
}

// ---------------- persistent LSTM scan: 8 blocks = (dir, batch) ----------------
__global__ __launch_bounds__(512) void k_scan(const float* __restrict__ gxf,
    const float* __restrict__ gxb,
    const float* __restrict__ whh_f, const float* __restrict__ whh_b,
    unsigned short* __restrict__ Yb)
{
  const int dir = blockIdx.x >> 2;
  const int b   = blockIdx.x & 3;
  const int j   = threadIdx.x;
  const float* whh = dir ? whh_b : whh_f;
  const float* G   = dir ? gxb : gxf;
  float w[128];
  {
    const float4* wp = (const float4*)(whh + (size_t)j*128);
    #pragma unroll
    for (int q=0;q<32;++q){ float4 v = wp[q]; w[4*q]=v.x; w[4*q+1]=v.y; w[4*q+2]=v.z; w[4*q+3]=v.w; }
  }
  __shared__ __align__(16) float hbuf[128];
  __shared__ float gbuf[512];
  if (j < 128) hbuf[j] = 0.f;
  float c = 0.f;
  __syncthreads();
  for (int t=0;t<512;++t){
    const int tt = dir ? (511-t) : t;
    float acc = G[((size_t)(b*512 + tt))*512 + j];
    const float4* hp = (const float4*)hbuf;
    #pragma unroll
    for (int q=0;q<32;++q){
      float4 hv = hp[q];
      acc += w[4*q]*hv.x + w[4*q+1]*hv.y + w[4*q+2]*hv.z + w[4*q+3]*hv.w;
    }
    gbuf[j] = acc;
    __syncthreads();
    if (j < 128){
      float ig = sigm(gbuf[j]);
      float fg = sigm(gbuf[j+128]);
      float gg = tanh_(gbuf[j+256]);
      float og = sigm(gbuf[j+384]);
      c = fg*c + ig*gg;
      float h = og * tanh_(c);
      hbuf[j] = h;
      Yb[((size_t)(b*512 + tt))*256 + dir*128 + j] = f2bf(h);
    }
    __syncthreads();
  }
}

// ---------------- final einsum: [2048,256] x [50000,256]^T via bf16 MFMA ----------------
__global__ __launch_bounds__(256) void k_einsum(const unsigned short* __restrict__ Yb,
    const unsigned short* __restrict__ Xb, float* __restrict__ out)
{
  const int wave = threadIdx.x >> 6;
  const int lane = threadIdx.x & 63;
  const int ntile = blockIdx.y*4 + wave;
  if (ntile >= 3125) return;
  const int m0 = blockIdx.x << 4;
  const int n0 = ntile << 4;
  const int la = lane & 15, q = lane >> 4;
  const bf16x8* pa = (const bf16x8*)(Yb + (size_t)(m0 + la)*256 + q*8);
  const bf16x8* pb = (const bf16x8*)(Xb + (size_t)(n0 + la)*256 + q*8);
  f32x4 acc = {0.f,0.f,0.f,0.f};
  #pragma unroll
  for (int kk=0; kk<8; ++kk){
    acc = __builtin_amdgcn_mfma_f32_16x16x32_bf16(pa[kk*4], pb[kk*4], acc, 0, 0, 0);
  }
  const int col = n0 + la;
  const size_t base = (size_t)(m0 + q*4)*50000 + col;
  out[base         ] = acc[0];
  out[base +  50000] = acc[1];
  out[base + 100000] = acc[2];
  out[base + 150000] = acc[3];
}

extern "C" void kernel_launch(void* const* d_in, const int* in_sizes, int n_in,
                              void* d_out, int out_size, void* d_ws, size_t ws_size,
                              hipStream_t stream) {
  const float* trace = (const float*)d_in[0];
  const float* x     = (const float*)d_in[1];
  const int*   ei    = (const int*)d_in[2];
  const float* c1wl = (const float*)d_in[3];
  const float* c1bl = (const float*)d_in[4];
  const float* c1wr = (const float*)d_in[5];
  const float* c2wl = (const float*)d_in[6];
  const float* c2bl = (const float*)d_in[7];
  const float* c2wr = (const float*)d_in[8];
  const float* s1w1 = (const float*)d_in[9];
  const float* s1b1 = (const float*)d_in[10];
  const float* s1w2 = (const float*)d_in[11];
  const float* s1b2 = (const float*)d_in[12];
  const float* s2w1 = (const float*)d_in[13];
  const float* s2b1 = (const float*)d_in[14];
  const float* s2w2 = (const float*)d_in[15];
  const float* s2b2 = (const float*)d_in[16];
  const float* bn1g = (const float*)d_in[17];
  const float* bn1b = (const float*)d_in[18];
  const float* bn2g = (const float*)d_in[19];
  const float* bn2b = (const float*)d_in[20];
  const float* wihf = (const float*)d_in[21];
  const float* whhf = (const float*)d_in[22];
  const float* bihf = (const float*)d_in[23];
  const float* bhhf = (const float*)d_in[24];
  const float* wihb = (const float*)d_in[25];
  const float* whhb = (const float*)d_in[26];
  const float* bihb = (const float*)d_in[27];
  const float* bhhb = (const float*)d_in[28];
  const int E = in_sizes[2] / 2;
  const int* srcv = ei;
  const int* dstv = ei + E;

  char* W = (char*)d_ws;
  int*   degi  = (int*)(W + 0);           // 50000 ints
  int*   offp  = (int*)(W + 200704);      // 50001 ints
  int*   cur   = (int*)(W + 401408);      // 50000 ints
  int*   eidx  = (int*)(W + 602112);      // 800000 ints
  float* stats = (float*)(W + 3802112);   // 2048 f: stats1, ab1, stats2, ab2
  float* mr1   = (float*)(W + 3810304);   // 50000x128 (mr1, later t2)
  float* SA    = (float*)(W + 29410304);  // u1, then mr2
  float* SB    = (float*)(W + 80610304);  // m1, then u2
  float* SC    = (float*)(W + 131810304); // t1, then x1, then m2
  float* gxf   = (float*)(W + 183010304); // 2048x512
  float* gxb   = gxf + (size_t)2048*512;
  unsigned short* x2bf = (unsigned short*)(W + 191398912); // 50000x256 bf16
  unsigned short* Ybf  = (unsigned short*)(W + 216998912); // 2048x256 bf16
  float* out = (float*)d_out;

  hipMemsetAsync(degi, 0, 200704, stream);
  hipMemsetAsync(stats, 0, 2048*sizeof(float), stream);

  k_count   <<<(E+255)/256, 256, 0, stream>>>(dstv, degi, E);
  k_scanoff <<<1, 1024, 0, stream>>>(degi, offp, cur);
  k_fill    <<<(E+255)/256, 256, 0, stream>>>(srcv, dstv, cur, eidx, E);

  // ---- layer 1 ----
  k_gmean128<<<N_NODES/8, 256, 0, stream>>>(x, offp, eidx, mr1);
  k_gemm<<<dim3(391,1), 256, 0, stream>>>(x,   s1w1, s1b1, nullptr, SC, N_NODES, 128, 128, GF_RELU); // t1
  k_gemm<<<dim3(391,2), 256, 0, stream>>>(mr1, c1wl, c1bl, nullptr, SA, N_NODES, 256, 128, 0);       // u1
  k_gemm<<<dim3(391,2), 256, 0, stream>>>(x,   c1wr, nullptr, nullptr, SA, N_NODES, 256, 128, GF_ACC); // u1 += x@wr^T
  k_gemm<<<dim3(391,2), 256, 0, stream>>>(SC,  s1w2, s1b2, nullptr, SB, N_NODES, 256, 128, 0);       // m1
  k_bnstats <<<256, 256, 0, stream>>>(SA, stats, N_NODES);
  k_bnparams<<<1, 256, 0, stream>>>(stats, bn1g, bn1b, stats+512, 1.0f/N_NODES);
  k_combine <<<N_NODES, 256, 0, stream>>>(SA, SB, stats+512, SC, (unsigned short*)nullptr);          // x1 -> SC

  // ---- layer 2 ----
  k_gmean256<<<N_NODES/4, 256, 0, stream>>>(SC, offp, eidx, SA);                                     // mr2 -> SA
  k_gemm<<<dim3(391,1), 256, 0, stream>>>(SC,  s2w1, s2b1, nullptr, mr1, N_NODES, 128, 256, GF_RELU); // t2
  k_gemm<<<dim3(391,2), 256, 0, stream>>>(SA,  c2wl, c2bl, nullptr, SB, N_NODES, 256, 256, 0);       // u2
  k_gemm<<<dim3(391,2), 256, 0, stream>>>(SC,  c2wr, nullptr, nullptr, SB, N_NODES, 256, 256, GF_ACC); // u2 += x1@wr^T
  k_gemm<<<dim3(391,2), 256, 0, stream>>>(mr1, s2w2, s2b2, nullptr, SC, N_NODES, 256, 128, 0);       // m2
  k_bnstats <<<256, 256, 0, stream>>>(SB, stats+1024, N_NODES);
  k_bnparams<<<1, 256, 0, stream>>>(stats+1024, bn2g, bn2b, stats+1536, 1.0f/N_NODES);
  k_combine <<<N_NODES, 256, 0, stream>>>(SB, SC, stats+1536, (float*)nullptr, x2bf);

  // ---- BiLSTM ----
  k_gemm<<<dim3(16,4), 256, 0, stream>>>(trace, wihf, bihf, bhhf, gxf, 2048, 512, 128, 0);
  k_gemm<<<dim3(16,4), 256, 0, stream>>>(trace, wihb, bihb, bhhb, gxb, 2048, 512, 128, 0);
  k_scan    <<<8, 512, 0, stream>>>(gxf, gxb, whhf, whhb, Ybf);

  k_einsum  <<<dim3(128, 782), 256, 0, stream>>>(Ybf, x2bf, out);

  (void)n_in; (void)out_size; (void)ws_size;
}